// Round 3
// baseline (209.535 us; speedup 1.0000x reference)
//
#include <hip/hip_runtime.h>
#include <hip/hip_bf16.h>

#define BATCH 32
#define KP1   8193              // K+1
#define FEAT  128
#define SDIM  2048
#define ENT   (BATCH * KP1)     // 262176 gather entries
#define TOT_OUT ENT
#define NBIN  4096
#define BINSHIFT 8              // bin = fi >> 8  (256 rows = 128 KB span)
#define NBLK_SORT 16
#define CHUNK ((ENT + NBLK_SORT - 1) / NBLK_SORT)   // 16386
#define NB_G  1024              // gather blocks (512 thr = 8 waves each)
#define EPH   17                // entries per 32-lane half (16384 halves)
#define NBLK_LOSS 512

__device__ __forceinline__ float wave_reduce64(float v) {
    #pragma unroll
    for (int off = 32; off > 0; off >>= 1) v += __shfl_xor(v, off);
    return v;
}

// ---------------- kernel 1: embed (linear + L2 norm) + zero bin counters ----
__global__ void embed_kernel(const float* __restrict__ x_s, const float* __restrict__ x_t,
                             const float* __restrict__ W_s, const float* __restrict__ b_s,
                             const float* __restrict__ W_t, const float* __restrict__ b_t,
                             float* __restrict__ f_out, int* __restrict__ bincnt) {
    __shared__ float xsh[SDIM];
    __shared__ float ysh[FEAT];
    __shared__ float red[4];
    int bid = blockIdx.x;          // 0..63
    int tid = threadIdx.x;
    // side job: zero the 4096 bin counters (64 blocks x 64 ints)
    if (tid < 64) bincnt[bid * 64 + tid] = 0;

    int m   = bid >> 5;            // 0 = student, 1 = teacher
    int b   = bid & 31;
    const float* x    = (m ? x_t : x_s) + (size_t)b * SDIM;
    const float* W    = m ? W_t : W_s;
    const float* bias = m ? b_t : b_s;
    float* f = f_out + (size_t)m * BATCH * FEAT + (size_t)b * FEAT;

    for (int i = tid; i < SDIM / 4; i += 256)
        ((float4*)xsh)[i] = ((const float4*)x)[i];
    __syncthreads();

    int wave = tid >> 6, lane = tid & 63;
    const float4* x4 = (const float4*)xsh;
    for (int d = wave; d < FEAT; d += 4) {
        const float4* Wr = (const float4*)(W + (size_t)d * SDIM);
        float acc = 0.f;
        #pragma unroll 8
        for (int i = lane; i < SDIM / 4; i += 64) {
            float4 w = Wr[i], xv = x4[i];
            acc += w.x * xv.x + w.y * xv.y + w.z * xv.z + w.w * xv.w;
        }
        acc = wave_reduce64(acc);
        if (lane == 0) ysh[d] = acc + bias[d];
    }
    __syncthreads();

    float v = 0.f;
    if (tid < FEAT) { float y = ysh[tid]; v = y * y; }
    v = wave_reduce64(v);
    if (lane == 0) red[wave] = v;
    __syncthreads();
    float sumsq = red[0] + red[1];
    float inv = 1.0f / sqrtf(sumsq);
    if (tid < FEAT) f[tid] = ysh[tid] * inv;
}

// ---------------- sort pass 1: count entries per bin ----------------
__global__ void count_kernel(const int* __restrict__ idx, const int* __restrict__ cidx,
                             int* __restrict__ bincnt) {
    __shared__ int cnt[NBIN];
    int tid = threadIdx.x;
    for (int i = tid; i < NBIN; i += 256) cnt[i] = 0;
    __syncthreads();
    int start = blockIdx.x * CHUNK;
    int end = start + CHUNK; if (end > ENT) end = ENT;
    for (int e = start + tid; e < end; e += 256) {
        int b = e / KP1, k = e - b * KP1;
        int fi = (k == 0) ? idx[b] : cidx[(size_t)b * 8192 + (k - 1)];
        atomicAdd(&cnt[fi >> BINSHIFT], 1);
    }
    __syncthreads();
    for (int i = tid; i < NBIN; i += 256)
        if (cnt[i]) atomicAdd(&bincnt[i], cnt[i]);
}

// ---------------- sort pass 2: exclusive scan of bin counts ----------------
__global__ void scan_kernel(const int* __restrict__ bincnt, int* __restrict__ glob_off) {
    __shared__ int s[1024];
    int t = threadIdx.x;
    int c0 = bincnt[4*t], c1 = bincnt[4*t+1], c2 = bincnt[4*t+2], c3 = bincnt[4*t+3];
    int tsum = c0 + c1 + c2 + c3;
    s[t] = tsum;
    __syncthreads();
    for (int d = 1; d < 1024; d <<= 1) {
        int v = s[t];
        int add = (t >= d) ? s[t - d] : 0;
        __syncthreads();
        s[t] = v + add;
        __syncthreads();
    }
    int excl = (t == 0) ? 0 : s[t - 1];
    glob_off[4*t]   = excl;
    glob_off[4*t+1] = excl + c0;
    glob_off[4*t+2] = excl + c0 + c1;
    glob_off[4*t+3] = excl + c0 + c1 + c2;
}

// ---------------- sort pass 3: scatter entries into bin order ----------------
__global__ void scatter_kernel(const int* __restrict__ idx, const int* __restrict__ cidx,
                               int* __restrict__ glob_off,
                               int* __restrict__ sorted_fi, int* __restrict__ sorted_bk) {
    __shared__ int cnt[NBIN];
    int tid = threadIdx.x;
    for (int i = tid; i < NBIN; i += 256) cnt[i] = 0;
    __syncthreads();
    int start = blockIdx.x * CHUNK;
    int end = start + CHUNK; if (end > ENT) end = ENT;
    // local count
    for (int e = start + tid; e < end; e += 256) {
        int b = e / KP1, k = e - b * KP1;
        int fi = (k == 0) ? idx[b] : cidx[(size_t)b * 8192 + (k - 1)];
        atomicAdd(&cnt[fi >> BINSHIFT], 1);
    }
    __syncthreads();
    // reserve global space per bin; cnt[i] becomes this block's running base
    for (int i = tid; i < NBIN; i += 256) {
        int c = cnt[i];
        cnt[i] = c ? atomicAdd(&glob_off[i], c) : 0;
    }
    __syncthreads();
    // scatter
    for (int e = start + tid; e < end; e += 256) {
        int b = e / KP1, k = e - b * KP1;
        int fi = (k == 0) ? idx[b] : cidx[(size_t)b * 8192 + (k - 1)];
        int pos = atomicAdd(&cnt[fi >> BINSHIFT], 1);
        sorted_fi[pos] = fi;
        sorted_bk[pos] = (b << 14) | k;
    }
}

// ---------------- kernel 2: gather in sorted order ----------------
__global__ __launch_bounds__(512) void gather_kernel(
        const float* __restrict__ mem_v1, const float* __restrict__ mem_v2,
        const float* __restrict__ f,   // f_s[32][128] then f_t[32][128]
        const int* __restrict__ sorted_fi, const int* __restrict__ sorted_bk,
        float* __restrict__ out_v1, float* __restrict__ out_v2,
        float* __restrict__ partials /* [NB_G][2] */) {
    const float INVT = 14.285714285714286f;  // 1/0.07
    __shared__ float fsh[2 * BATCH * FEAT];  // 32 KB
    __shared__ float ls1[8], ls2[8];
    int tid = threadIdx.x;
    for (int i = tid; i < 2 * BATCH * FEAT / 4; i += 512)
        ((float4*)fsh)[i] = ((const float4*)f)[i];
    __syncthreads();

    int halfg = (blockIdx.x * 512 + tid) >> 5;   // global 32-lane half id
    int l32 = tid & 31;
    int e0 = halfg * EPH;
    int e1 = e0 + EPH; if (e1 > ENT) e1 = ENT;

    float s1 = 0.f, s2 = 0.f;
    for (int e = e0; e < e1; e += 2) {
        int fi0 = sorted_fi[e];
        int bk0 = sorted_bk[e];
        int have1 = (e + 1 < e1);
        int fi1 = sorted_fi[have1 ? e + 1 : e];
        int bk1 = sorted_bk[have1 ? e + 1 : e];

        const float4* r10 = (const float4*)(mem_v1 + (size_t)fi0 * FEAT);
        const float4* r20 = (const float4*)(mem_v2 + (size_t)fi0 * FEAT);
        const float4* r11 = (const float4*)(mem_v1 + (size_t)fi1 * FEAT);
        const float4* r21 = (const float4*)(mem_v2 + (size_t)fi1 * FEAT);
        float4 a10 = r10[l32];
        float4 a20 = r20[l32];
        float4 a11 = r11[l32];
        float4 a21 = r21[l32];

        int b0 = bk0 >> 14, k0 = bk0 & 16383;
        int b1 = bk1 >> 14, k1 = bk1 & 16383;
        float4 ft0 = ((const float4*)(fsh + BATCH * FEAT + b0 * FEAT))[l32];
        float4 fs0 = ((const float4*)(fsh + b0 * FEAT))[l32];
        float4 ft1 = ((const float4*)(fsh + BATCH * FEAT + b1 * FEAT))[l32];
        float4 fs1 = ((const float4*)(fsh + b1 * FEAT))[l32];

        float dt0 = a10.x*ft0.x + a10.y*ft0.y + a10.z*ft0.z + a10.w*ft0.w;
        float ds0 = a20.x*fs0.x + a20.y*fs0.y + a20.z*fs0.z + a20.w*fs0.w;
        float dt1 = a11.x*ft1.x + a11.y*ft1.y + a11.z*ft1.z + a11.w*ft1.w;
        float ds1 = a21.x*fs1.x + a21.y*fs1.y + a21.z*fs1.z + a21.w*fs1.w;
        #pragma unroll
        for (int off = 16; off > 0; off >>= 1) {
            dt0 += __shfl_xor(dt0, off);
            ds0 += __shfl_xor(ds0, off);
            dt1 += __shfl_xor(dt1, off);
            ds1 += __shfl_xor(ds1, off);
        }
        float ov20 = expf(dt0 * INVT);
        float ov10 = expf(ds0 * INVT);
        float ov21 = expf(dt1 * INVT);
        float ov11 = expf(ds1 * INVT);
        if (l32 == 0) {
            out_v2[b0 * KP1 + k0] = ov20;
            out_v1[b0 * KP1 + k0] = ov10;
            s1 += ov10; s2 += ov20;
            if (have1) {
                out_v2[b1 * KP1 + k1] = ov21;
                out_v1[b1 * KP1 + k1] = ov11;
                s1 += ov11; s2 += ov21;
            }
        }
    }
    s1 = wave_reduce64(s1);
    s2 = wave_reduce64(s2);
    int wave = tid >> 6, lane = tid & 63;
    if (lane == 0) { ls1[wave] = s1; ls2[wave] = s2; }
    __syncthreads();
    if (tid == 0) {
        float t1 = 0.f, t2 = 0.f;
        #pragma unroll
        for (int w = 0; w < 8; ++w) { t1 += ls1[w]; t2 += ls2[w]; }
        partials[2 * blockIdx.x + 0] = t1;
        partials[2 * blockIdx.x + 1] = t2;
    }
}

// ---------------- kernel 3: reduce partials -> Z ----------------
__global__ void zreduce_kernel(const float* __restrict__ partials, float* __restrict__ Z) {
    __shared__ float sh1[256], sh2[256];
    int t = threadIdx.x;
    float a1 = 0.f, a2 = 0.f;
    for (int i = t; i < NB_G; i += 256) { a1 += partials[2*i]; a2 += partials[2*i+1]; }
    sh1[t] = a1; sh2[t] = a2; __syncthreads();
    for (int s = 128; s > 0; s >>= 1) {
        if (t < s) { sh1[t] += sh1[t+s]; sh2[t] += sh2[t+s]; }
        __syncthreads();
    }
    if (t == 0) {
        const float scale = 1000000.0f / (float)TOT_OUT;  // mean * N_DATA
        Z[0] = sh1[0] * scale;   // Z_v1 (for out_v1 -> out_s)
        Z[1] = sh2[0] * scale;   // Z_v2 (for out_v2 -> out_t)
    }
}

// ---------------- kernel 4: per-element loss terms ----------------
__global__ void loss_kernel(const float* __restrict__ out_v1, const float* __restrict__ out_v2,
                            const float* __restrict__ Z, double* __restrict__ lpart) {
    const float cc = 8192.0f / 1000000.0f;   // m * Pn
    const float ce = cc + 1e-7f;             // c + EPS
    float z0 = Z[0], z1 = Z[1];
    int gid = blockIdx.x * blockDim.x + threadIdx.x;
    int stride = gridDim.x * blockDim.x;
    double acc = 0.0;
    for (int e = gid; e < 2 * TOT_OUT; e += stride) {
        int arr = (e >= TOT_OUT);
        int r   = arr ? (e - TOT_OUT) : e;
        int k   = r % KP1;
        float o = (arr ? out_v2[r] : out_v1[r]) / (arr ? z1 : z0);
        float denom = o + ce;
        float term = (k == 0) ? logf(o / denom) : logf(cc / denom);
        acc += (double)term;
    }
    __shared__ double sh[256];
    sh[threadIdx.x] = acc; __syncthreads();
    for (int s = 128; s > 0; s >>= 1) {
        if (threadIdx.x < s) sh[threadIdx.x] += sh[threadIdx.x + s];
        __syncthreads();
    }
    if (threadIdx.x == 0) lpart[blockIdx.x] = sh[0];
}

// ---------------- kernel 5: final reduce -> loss ----------------
__global__ void final_kernel(const double* __restrict__ lpart, float* __restrict__ out) {
    __shared__ double sh[256];
    double acc = 0.0;
    for (int i = threadIdx.x; i < NBLK_LOSS; i += 256) acc += lpart[i];
    sh[threadIdx.x] = acc; __syncthreads();
    for (int s = 128; s > 0; s >>= 1) {
        if (threadIdx.x < s) sh[threadIdx.x] += sh[threadIdx.x + s];
        __syncthreads();
    }
    if (threadIdx.x == 0) out[0] = (float)(-sh[0] / (double)BATCH);
}

extern "C" void kernel_launch(void* const* d_in, const int* in_sizes, int n_in,
                              void* d_out, int out_size, void* d_ws, size_t ws_size,
                              hipStream_t stream) {
    const float* x_s   = (const float*)d_in[0];
    const float* x_t   = (const float*)d_in[1];
    const float* W_s   = (const float*)d_in[2];
    const float* b_s   = (const float*)d_in[3];
    const float* W_t   = (const float*)d_in[4];
    const float* b_t   = (const float*)d_in[5];
    const float* mem_v1 = (const float*)d_in[6];
    const float* mem_v2 = (const float*)d_in[7];
    const int*   idx   = (const int*)d_in[8];
    const int*   cidx  = (const int*)d_in[9];
    float* out = (float*)d_out;

    // workspace layout
    float* ws = (float*)d_ws;
    float* f      = ws;                          // 8192 floats
    float* out_v1 = f + 2 * BATCH * FEAT;        // 262176
    float* out_v2 = out_v1 + TOT_OUT;            // 262176
    float* parts  = out_v2 + TOT_OUT;            // 2*NB_G = 2048
    float* Z      = parts + 2 * NB_G;            // 2
    size_t off_f  = (size_t)(Z + 2 - ws);
    off_f = (off_f + 1) & ~(size_t)1;            // 8B align
    double* lpart = (double*)(ws + off_f);       // 512 doubles = 1024 floats
    int* bincnt    = (int*)(ws + off_f + 2 * NBLK_LOSS);
    int* glob_off  = bincnt + NBIN;
    int* sorted_fi = glob_off + NBIN;
    int* sorted_bk = sorted_fi + ENT;

    embed_kernel<<<64, 256, 0, stream>>>(x_s, x_t, W_s, b_s, W_t, b_t, f, bincnt);
    count_kernel<<<NBLK_SORT, 256, 0, stream>>>(idx, cidx, bincnt);
    scan_kernel<<<1, 1024, 0, stream>>>(bincnt, glob_off);
    scatter_kernel<<<NBLK_SORT, 256, 0, stream>>>(idx, cidx, glob_off, sorted_fi, sorted_bk);
    gather_kernel<<<NB_G, 512, 0, stream>>>(mem_v1, mem_v2, f, sorted_fi, sorted_bk,
                                            out_v1, out_v2, parts);
    zreduce_kernel<<<1, 256, 0, stream>>>(parts, Z);
    loss_kernel<<<NBLK_LOSS, 256, 0, stream>>>(out_v1, out_v2, Z, lpart);
    final_kernel<<<1, 256, 0, stream>>>(lpart, out);
}

// Round 4
// 124.933 us; speedup vs baseline: 1.6772x; 1.6772x over previous
//
#include <hip/hip_runtime.h>
#include <hip/hip_bf16.h>

#define BATCH 32
#define KP1   8193      // K+1
#define FEAT  128
#define SDIM  2048
#define KT    64        // k tiles per batch row (128 k each; last tile +1)
#define NBLK_GATHER (KT * BATCH)   // 2048
#define NBLK_LOSS   256
#define TOT_OUT (BATCH * KP1)      // 262176

__device__ __forceinline__ float wave_reduce64(float v) {
    #pragma unroll
    for (int off = 32; off > 0; off >>= 1) v += __shfl_xor(v, off);
    return v;
}

// ---------------- kernel 1: embed (linear + L2 norm) ----------------
__global__ void embed_kernel(const float* __restrict__ x_s, const float* __restrict__ x_t,
                             const float* __restrict__ W_s, const float* __restrict__ b_s,
                             const float* __restrict__ W_t, const float* __restrict__ b_t,
                             float* __restrict__ f_out /* f_s[32][128] then f_t[32][128] */) {
    __shared__ float xsh[SDIM];
    __shared__ float ysh[FEAT];
    __shared__ float red[4];
    int bid = blockIdx.x;          // 0..63
    int m   = bid >> 5;            // 0 = student, 1 = teacher
    int b   = bid & 31;
    const float* x    = (m ? x_t : x_s) + (size_t)b * SDIM;
    const float* W    = m ? W_t : W_s;
    const float* bias = m ? b_t : b_s;
    float* f = f_out + (size_t)m * BATCH * FEAT + (size_t)b * FEAT;

    int tid = threadIdx.x;
    for (int i = tid; i < SDIM / 4; i += 256)
        ((float4*)xsh)[i] = ((const float4*)x)[i];
    __syncthreads();

    int wave = tid >> 6, lane = tid & 63;
    const float4* x4 = (const float4*)xsh;
    for (int d = wave; d < FEAT; d += 4) {
        const float4* Wr = (const float4*)(W + (size_t)d * SDIM);
        float acc = 0.f;
        #pragma unroll 8
        for (int i = lane; i < SDIM / 4; i += 64) {
            float4 w = Wr[i], xv = x4[i];
            acc += w.x * xv.x + w.y * xv.y + w.z * xv.z + w.w * xv.w;
        }
        acc = wave_reduce64(acc);
        if (lane == 0) ysh[d] = acc + bias[d];
    }
    __syncthreads();

    float v = 0.f;
    if (tid < FEAT) { float y = ysh[tid]; v = y * y; }
    v = wave_reduce64(v);
    if (lane == 0) red[wave] = v;
    __syncthreads();
    float sumsq = red[0] + red[1];
    float inv = 1.0f / sqrtf(sumsq);
    if (tid < FEAT) f[tid] = ysh[tid] * inv;
}

// ---------------- kernel 2: gather + dot + exp + partial sums ----------------
// Block = 256 thr (4 waves). Each 32-lane half owns one k per iter ->
// 8 k's per block-iteration, float4 row loads (512 B row = 32 lanes x 16 B).
__global__ void gather_kernel(const float* __restrict__ mem_v1, const float* __restrict__ mem_v2,
                              const float* __restrict__ f,   // f_s then f_t
                              const int* __restrict__ idx, const int* __restrict__ cidx,
                              float* __restrict__ out_v1, float* __restrict__ out_v2,
                              float* __restrict__ partials /* [NBLK_GATHER][2] */) {
    const float INVT = 14.285714285714286f;  // 1/0.07
    __shared__ int   kidx[132];
    __shared__ float ls1[4], ls2[4];
    int tile = blockIdx.x;    // 0..63
    int b    = blockIdx.y;    // 0..31
    int tid  = threadIdx.x;

    int k0 = tile * 128;
    int kn = (tile == KT - 1) ? 129 : 128;   // last tile also covers k=8192

    // prefetch this tile's indices into LDS
    if (tid < kn) {
        int k = k0 + tid;
        kidx[tid] = (k == 0) ? idx[b] : cidx[(size_t)b * 8192 + (k - 1)];
    }

    int wave = tid >> 6, lane = tid & 63, half = lane >> 5, l32 = lane & 31;
    const float4 fs4 = ((const float4*)(f + (size_t)b * FEAT))[l32];
    const float4 ft4 = ((const float4*)(f + (size_t)BATCH * FEAT + (size_t)b * FEAT))[l32];
    __syncthreads();

    float s1 = 0.f, s2 = 0.f;
    int iters = (kn + 7) >> 3;
    #pragma unroll 2
    for (int it = 0; it < iters; ++it) {
        int kl = (it << 3) + (wave << 1) + half;
        int valid = (kl < kn);
        int fi = kidx[valid ? kl : 0];
        const float4* r1 = (const float4*)(mem_v1 + (size_t)fi * FEAT);
        const float4* r2 = (const float4*)(mem_v2 + (size_t)fi * FEAT);
        float4 a1 = r1[l32];
        float4 a2 = r2[l32];
        float dt = a1.x * ft4.x + a1.y * ft4.y + a1.z * ft4.z + a1.w * ft4.w; // v1·f_t -> out_v2
        float ds = a2.x * fs4.x + a2.y * fs4.y + a2.z * fs4.z + a2.w * fs4.w; // v2·f_s -> out_v1
        #pragma unroll
        for (int off = 16; off > 0; off >>= 1) {
            dt += __shfl_xor(dt, off);
            ds += __shfl_xor(ds, off);
        }
        float ov2 = expf(dt * INVT);
        float ov1 = expf(ds * INVT);
        if (valid && l32 == 0) {
            out_v2[(size_t)b * KP1 + k0 + kl] = ov2;
            out_v1[(size_t)b * KP1 + k0 + kl] = ov1;
            s1 += ov1; s2 += ov2;
        }
    }
    s1 = wave_reduce64(s1);
    s2 = wave_reduce64(s2);
    if (lane == 0) { ls1[wave] = s1; ls2[wave] = s2; }
    __syncthreads();
    if (tid == 0) {
        int pbid = b * KT + tile;
        partials[2 * pbid + 0] = ls1[0] + ls1[1] + ls1[2] + ls1[3];
        partials[2 * pbid + 1] = ls2[0] + ls2[1] + ls2[2] + ls2[3];
    }
}

// ---------------- kernel 3: fused Z-reduce + per-element loss terms ----------
// Every block redundantly reduces the 2048x2 partials (deterministic, identical
// order in all blocks, served from L2) -> Z, then grid-strides the loss terms.
__global__ void lossZ_kernel(const float* __restrict__ partials,
                             const float* __restrict__ out_v1, const float* __restrict__ out_v2,
                             double* __restrict__ lpart) {
    __shared__ float sh1[256], sh2[256];
    __shared__ float zsh[2];
    int tid = threadIdx.x;
    float a1 = 0.f, a2 = 0.f;
    #pragma unroll
    for (int i = 0; i < NBLK_GATHER / 256; ++i) {
        int j = i * 256 + tid;
        a1 += partials[2 * j];
        a2 += partials[2 * j + 1];
    }
    sh1[tid] = a1; sh2[tid] = a2; __syncthreads();
    for (int s = 128; s > 0; s >>= 1) {
        if (tid < s) { sh1[tid] += sh1[tid + s]; sh2[tid] += sh2[tid + s]; }
        __syncthreads();
    }
    if (tid == 0) {
        const float scale = 1000000.0f / (float)TOT_OUT;  // mean * N_DATA
        zsh[0] = sh1[0] * scale;   // Z_v1
        zsh[1] = sh2[0] * scale;   // Z_v2
    }
    __syncthreads();
    float z0 = zsh[0], z1 = zsh[1];

    const float cc = 8192.0f / 1000000.0f;   // m * Pn
    const float ce = cc + 1e-7f;             // c + EPS
    int gid = blockIdx.x * 256 + tid;
    int stride = gridDim.x * 256;
    double acc = 0.0;
    for (int e = gid; e < 2 * TOT_OUT; e += stride) {
        int arr = (e >= TOT_OUT);
        int r   = arr ? (e - TOT_OUT) : e;
        int k   = r % KP1;
        float o = (arr ? out_v2[r] : out_v1[r]) / (arr ? z1 : z0);
        float denom = o + ce;
        float term = (k == 0) ? logf(o / denom) : logf(cc / denom);
        acc += (double)term;
    }
    __shared__ double shd[256];
    shd[tid] = acc; __syncthreads();
    for (int s = 128; s > 0; s >>= 1) {
        if (tid < s) shd[tid] += shd[tid + s];
        __syncthreads();
    }
    if (tid == 0) lpart[blockIdx.x] = shd[0];
}

// ---------------- kernel 4: final reduce -> loss ----------------
__global__ void final_kernel(const double* __restrict__ lpart, float* __restrict__ out) {
    __shared__ double sh[256];
    int tid = threadIdx.x;
    sh[tid] = lpart[tid];   // NBLK_LOSS == 256
    __syncthreads();
    for (int s = 128; s > 0; s >>= 1) {
        if (tid < s) sh[tid] += sh[tid + s];
        __syncthreads();
    }
    if (tid == 0) out[0] = (float)(-sh[0] / (double)BATCH);
}

extern "C" void kernel_launch(void* const* d_in, const int* in_sizes, int n_in,
                              void* d_out, int out_size, void* d_ws, size_t ws_size,
                              hipStream_t stream) {
    const float* x_s   = (const float*)d_in[0];
    const float* x_t   = (const float*)d_in[1];
    const float* W_s   = (const float*)d_in[2];
    const float* b_s   = (const float*)d_in[3];
    const float* W_t   = (const float*)d_in[4];
    const float* b_t   = (const float*)d_in[5];
    const float* mem_v1 = (const float*)d_in[6];
    const float* mem_v2 = (const float*)d_in[7];
    const int*   idx   = (const int*)d_in[8];
    const int*   cidx  = (const int*)d_in[9];
    float* out = (float*)d_out;

    // workspace layout (floats)
    float* ws = (float*)d_ws;
    float* f      = ws;                         // 2*32*128 = 8192
    float* out_v1 = f + 2 * BATCH * FEAT;       // 262176
    float* out_v2 = out_v1 + TOT_OUT;           // 262176
    float* parts  = out_v2 + TOT_OUT;           // 2*2048 = 4096
    size_t off_f = (size_t)(parts + 2 * NBLK_GATHER - ws);
    off_f = (off_f + 1) & ~(size_t)1;           // 8B align
    double* lpart = (double*)(ws + off_f);      // 256 doubles

    embed_kernel<<<64, 256, 0, stream>>>(x_s, x_t, W_s, b_s, W_t, b_t, f);
    gather_kernel<<<dim3(KT, BATCH), 256, 0, stream>>>(mem_v1, mem_v2, f, idx, cidx,
                                                        out_v1, out_v2, parts);
    lossZ_kernel<<<NBLK_LOSS, 256, 0, stream>>>(parts, out_v1, out_v2, lpart);
    final_kernel<<<1, 256, 0, stream>>>(lpart, out);
}